// Round 8
// baseline (9673.945 us; speedup 1.0000x reference)
//
#include <hip/hip_runtime.h>
#include <hip/hip_fp16.h>

// RNN_14078902797083: 2-layer tanh RNN + FC + softmax, fp32 in/out.
// B=64, T=2048, IN=256, H=512, NCLASS=2.
//
// R12: halve the scan's DS-broadcast instruction count. R11 closed the
// model: scan is DS-issue bound (264 uniform ds_read_b128/step/CU ~= 3100
// cyc). Broadcast floor per wave = 32 instrs (512 B of h / 16 B), so the
// lever is FEWER WAVES: 256 threads (4 waves), each thread owns 2 rows
// (j, j+256) -> same 32 broadcasts feed 256 sdot4, DS/step/CU = 128.
// h stored PERMUTED (byte 2j = row j, 2j+1 = row j+256) so each thread
// publishes with one ds_write_b16; weights packed in matching order at
// setup (dword c = rows {2c, 256+2c, 2c+1, 257+2c}) — numerics identical
// to R11. __launch_bounds__(256,1): 512-VGPR budget for 256 weight dwords
// + working set (AGPR overflow is free: CDNA VALU reads AGPRs directly).

#define BB 64
#define TT 2048
#define IN 256
#define HH 512
#define MM (BB * TT)          // 131072 rows

// workspace layout (bytes)
#define BUF0_OFF 0ull                      // [B][T][H] f32 = 256 MB (xw0 -> h1 -> xw1, in place)
#define WT_OFF   268435456ull              // W^T scratch, 1 MB
#define H2L_OFF  269484032ull              // [B][H] f32 last hidden = 128 KB

__device__ __forceinline__ int sd4(unsigned a, unsigned b, int c) {
#if __has_builtin(__builtin_amdgcn_sdot4)
    return __builtin_amdgcn_sdot4((int)a, (int)b, c, false);
#else
    const int a0 = (int)(char)(a), a1 = (int)(char)(a >> 8);
    const int a2 = (int)(char)(a >> 16), a3 = (int)(char)(a >> 24);
    const int b0 = (int)(char)(b), b1 = (int)(char)(b >> 8);
    const int b2 = (int)(char)(b >> 16), b3 = (int)(char)(b >> 24);
    return c + a0 * b0 + a1 * b1 + a2 * b2 + a3 * b3;
#endif
}

// fast tanh: copysign((1-e)/(1+e), x), e = exp(-2|x|). No overflow; ~2e-6 abs err.
__device__ __forceinline__ float fast_tanh(float x) {
    const float ax = __builtin_fabsf(x);
    const float e  = __expf(-2.f * ax);
    const float r  = (1.f - e) * __builtin_amdgcn_rcpf(1.f + e);
    return __builtin_copysignf(r, x);
}

__device__ __forceinline__ unsigned pkq4(float s, float x0, float x1, float x2, float x3) {
    const int q0 = (int)rintf(x0 * s), q1 = (int)rintf(x1 * s);
    const int q2 = (int)rintf(x2 * s), q3 = (int)rintf(x3 * s);
    return (unsigned)(q0 & 0xFF) | ((unsigned)(q1 & 0xFF) << 8) |
           ((unsigned)(q2 & 0xFF) << 16) | ((unsigned)(q3 & 0xFF) << 24);
}

// -------------------- W transpose: W[512][K] -> WT[K][512] --------------------
__global__ void transpose_w(const float* __restrict__ W, float* __restrict__ WT, int K)
{
    __shared__ float tile[32][33];
    const int k0 = blockIdx.x * 32;
    const int c0 = blockIdx.y * 32;
    const int tx = threadIdx.x & 31;
    const int ty = threadIdx.x >> 5;          // 0..7
    #pragma unroll
    for (int i = ty; i < 32; i += 8)
        tile[i][tx] = W[(size_t)(c0 + i) * K + k0 + tx];   // coalesced along k
    __syncthreads();
    #pragma unroll
    for (int i = ty; i < 32; i += 8)
        WT[(size_t)(k0 + i) * HH + c0 + tx] = tile[tx][i]; // coalesced along c
}

// -------------------- input projection GEMM: out = A @ W^T + (b1+b2) ----------
// A [M][K] (may alias out), WT [K][512], out [M][512]. 32 rows/WG, full N.
// Full-K A staging in LDS BEFORE any write -> in-place safe per 32-row block.
template <int K>
__global__ __launch_bounds__(256, 2)
void gemm_xw(const float* A, const float* __restrict__ WT,
             const float* __restrict__ b1, const float* __restrict__ b2,
             float* out)
{
    extern __shared__ char smem[];
    float* As = (float*)smem;                 // [32][K]
    const int m0 = blockIdx.x * 32;
    const int tid = threadIdx.x;

    const float* Ab = A + (size_t)m0 * K;
    #pragma unroll
    for (int i = 0; i < (32 * K) / 1024; ++i) {
        const int idx = tid * 4 + i * 1024;
        *(float4*)&As[idx] = *(const float4*)&Ab[idx];
    }
    __syncthreads();

    const int tc = tid & 63;                  // col base lane; cols c = tc + 64*cc
    const int r0 = (tid >> 6) * 8;            // 8 rows per thread

    float acc[8][8];
    #pragma unroll
    for (int cc = 0; cc < 8; ++cc) {
        const int c = tc + 64 * cc;
        const float bb = b1[c] + b2[c];
        #pragma unroll
        for (int rr = 0; rr < 8; ++rr) acc[rr][cc] = bb;
    }

    #pragma unroll 2
    for (int k = 0; k < K; k += 4) {
        float4 av4[8];
        #pragma unroll
        for (int rr = 0; rr < 8; ++rr)
            av4[rr] = *(const float4*)&As[(r0 + rr) * K + k];   // wave-uniform: broadcast
        #pragma unroll
        for (int kk = 0; kk < 4; ++kk) {
            float wv[8];
            #pragma unroll
            for (int cc = 0; cc < 8; ++cc)
                wv[cc] = WT[(size_t)(k + kk) * HH + tc + 64 * cc];  // lane-consecutive: coalesced
            #pragma unroll
            for (int rr = 0; rr < 8; ++rr) {
                const float a = ((const float*)&av4[rr])[kk];
                #pragma unroll
                for (int cc = 0; cc < 8; ++cc)
                    acc[rr][cc] = fmaf(a, wv[cc], acc[rr][cc]);
            }
        }
    }

    #pragma unroll
    for (int rr = 0; rr < 8; ++rr) {
        float* orow = out + (size_t)(m0 + r0 + rr) * HH;
        #pragma unroll
        for (int cc = 0; cc < 8; ++cc)
            orow[tc + 64 * cc] = acc[rr][cc];
    }
}

// -------------------- recurrent scan: 256 threads, 2 rows/thread, int8 --------
// Thread j owns rows j and j+256; 256 int8-packed weight dwords in registers
// (permuted packing). h stored permuted in LDS: byte 2j = row j, 2j+1 = j+256.
template <bool WRITE_SEQ>
__global__ __launch_bounds__(256, 1)
void scan_rnn(const float* xw,                 // [B][T][H]; aliased by hseq when WRITE_SEQ
              const float* __restrict__ Whh,   // [H][H]
              float* hseq)                     // WRITE_SEQ: [B][T][H] (alias of xw); else [B][H]
{
    __shared__ alignas(16) unsigned hq[2][128];   // [parity][512 int8, permuted]

    const int b = blockIdx.x;
    const int j = threadIdx.x;                 // 0..255: rows j and j+256

    // ---- one-time: quantize both weight rows to int8 (permuted packing) ----
    const float* wr0 = Whh + (size_t)j * HH;
    const float* wr1 = Whh + (size_t)(j + 256) * HH;
    float mx0 = 1e-20f, mx1 = 1e-20f;
    #pragma unroll
    for (int c = 0; c < 128; ++c) {
        const float4 f0 = *(const float4*)(wr0 + 4 * c);
        const float4 f1 = *(const float4*)(wr1 + 4 * c);
        mx0 = fmaxf(mx0, fmaxf(fmaxf(__builtin_fabsf(f0.x), __builtin_fabsf(f0.y)),
                               fmaxf(__builtin_fabsf(f0.z), __builtin_fabsf(f0.w))));
        mx1 = fmaxf(mx1, fmaxf(fmaxf(__builtin_fabsf(f1.x), __builtin_fabsf(f1.y)),
                               fmaxf(__builtin_fabsf(f1.z), __builtin_fabsf(f1.w))));
    }
    const float inv0 = 127.f / mx0, scale0 = mx0 / 16129.f;
    const float inv1 = 127.f / mx1, scale1 = mx1 / 16129.f;
    // permuted pack: dword c holds original columns {2c, 256+2c, 2c+1, 257+2c}
    unsigned w8a[128], w8b[128];
    #pragma unroll
    for (int c = 0; c < 128; ++c) {
        w8a[c] = pkq4(inv0, wr0[2 * c], wr0[256 + 2 * c], wr0[2 * c + 1], wr0[257 + 2 * c]);
        w8b[c] = pkq4(inv1, wr1[2 * c], wr1[256 + 2 * c], wr1[2 * c + 1], wr1[257 + 2 * c]);
    }

    const float* xrow0 = xw + (size_t)b * TT * HH + j;
    const float* xrow1 = xrow0 + 256;
    float* srow0 = WRITE_SEQ ? (hseq + (size_t)b * TT * HH + j) : nullptr;
    float* srow1 = WRITE_SEQ ? (srow0 + 256) : nullptr;

    float x0c = xrow0[0], x0n = xrow0[HH];
    float x1c = xrow1[0], x1n = xrow1[HH];
    __syncthreads();

    for (int t = 0; t < TT; ++t) {
        const int t2 = (t + 2 < TT) ? (t + 2) : (TT - 1);
        const float x0n2 = xrow0[(size_t)t2 * HH];       // 2-deep prefetch
        const float x1n2 = xrow1[(size_t)t2 * HH];

        float z0 = x0c, z1 = x1c;
        if (t > 0) {
            const unsigned* hp = hq[(t & 1) ^ 1];        // parity (t-1)&1
            int acc0 = 0, acc1 = 0;
            #pragma unroll
            for (int c = 0; c < 32; ++c) {
                const uint4 hb = *(const uint4*)(hp + 4 * c);   // uniform: LDS broadcast
                acc0 = sd4(w8a[4 * c + 0], hb.x, acc0);
                acc1 = sd4(w8b[4 * c + 0], hb.x, acc1);
                acc0 = sd4(w8a[4 * c + 1], hb.y, acc0);
                acc1 = sd4(w8b[4 * c + 1], hb.y, acc1);
                acc0 = sd4(w8a[4 * c + 2], hb.z, acc0);
                acc1 = sd4(w8b[4 * c + 2], hb.z, acc1);
                acc0 = sd4(w8a[4 * c + 3], hb.w, acc0);
                acc1 = sd4(w8b[4 * c + 3], hb.w, acc1);
            }
            z0 += (float)acc0 * scale0;
            z1 += (float)acc1 * scale1;
        }
        const float h0 = fast_tanh(z0);
        const float h1 = fast_tanh(z1);

        // quantize both rows, publish as ONE b16 write at permuted position 2j
        const int q0 = (int)rintf(fminf(fmaxf(h0 * 127.f, -127.f), 127.f));
        const int q1 = (int)rintf(fminf(fmaxf(h1 * 127.f, -127.f), 127.f));
        ((unsigned short*)hq[t & 1])[j] =
            (unsigned short)((q0 & 0xFF) | ((q1 & 0xFF) << 8));

        if (WRITE_SEQ) {
            srow0[(size_t)t * HH] = h0;        // in-place over xw: thread-local elements
            srow1[(size_t)t * HH] = h1;
        } else if (t == TT - 1) {
            hseq[b * HH + j]       = h0;
            hseq[b * HH + j + 256] = h1;
        }
        x0c = x0n; x0n = x0n2;
        x1c = x1n; x1n = x1n2;
        __syncthreads();
    }
}

// -------------------- FC + softmax --------------------
__global__ void fc_kernel(const float* __restrict__ h2, const float* __restrict__ w,
                          const float* __restrict__ bvec, float* __restrict__ out)
{
    const int b = threadIdx.x;   // 64 threads
    float z0 = bvec[0], z1 = bvec[1];
    #pragma unroll 4
    for (int k = 0; k < HH; k += 4) {
        float4 h  = *(const float4*)&h2[b * HH + k];
        float4 w0 = *(const float4*)&w[k];
        float4 w1 = *(const float4*)&w[HH + k];
        z0 += h.x * w0.x + h.y * w0.y + h.z * w0.z + h.w * w0.w;
        z1 += h.x * w1.x + h.y * w1.y + h.z * w1.z + h.w * w1.w;
    }
    const float m  = fmaxf(z0, z1);
    const float e0 = expf(z0 - m), e1 = expf(z1 - m);
    const float inv = 1.f / (e0 + e1);
    out[b * 2 + 0] = e0 * inv;
    out[b * 2 + 1] = e1 * inv;
}

extern "C" void kernel_launch(void* const* d_in, const int* in_sizes, int n_in,
                              void* d_out, int out_size, void* d_ws, size_t ws_size,
                              hipStream_t stream)
{
    (void)in_sizes; (void)n_in; (void)out_size; (void)ws_size;
    const float* x    = (const float*)d_in[0];
    const float* Wih0 = (const float*)d_in[1];
    const float* Whh0 = (const float*)d_in[2];
    const float* bih0 = (const float*)d_in[3];
    const float* bhh0 = (const float*)d_in[4];
    const float* Wih1 = (const float*)d_in[5];
    const float* Whh1 = (const float*)d_in[6];
    const float* bih1 = (const float*)d_in[7];
    const float* bhh1 = (const float*)d_in[8];
    const float* fcw  = (const float*)d_in[9];
    const float* fcb  = (const float*)d_in[10];
    float* out = (float*)d_out;

    char* ws = (char*)d_ws;
    float* buf0 = (float*)(ws + BUF0_OFF);
    float* WT   = (float*)(ws + WT_OFF);
    float* h2l  = (float*)(ws + H2L_OFF);

    // ---- layer 0 ----
    transpose_w<<<dim3(IN / 32, HH / 32), dim3(256), 0, stream>>>(Wih0, WT, IN);
    gemm_xw<IN><<<dim3(MM / 32), dim3(256), 32 * IN * 4, stream>>>(x, WT, bih0, bhh0, buf0);
    scan_rnn<true><<<dim3(BB), dim3(256), 0, stream>>>(buf0, Whh0, buf0);

    // ---- layer 1 (WT buffer reused: lifetimes disjoint) ----
    transpose_w<<<dim3(HH / 32, HH / 32), dim3(256), 0, stream>>>(Wih1, WT, HH);
    gemm_xw<HH><<<dim3(MM / 32), dim3(256), 32 * HH * 4, stream>>>(buf0, WT, bih1, bhh1, buf0);
    scan_rnn<false><<<dim3(BB), dim3(256), 0, stream>>>(buf0, Whh1, h2l);

    // ---- FC + softmax ----
    fc_kernel<<<dim3(1), dim3(64), 0, stream>>>(h2l, fcw, fcb, out);
}

// Round 9
// 6273.031 us; speedup vs baseline: 1.5421x; 1.5421x over previous
//
#include <hip/hip_runtime.h>
#include <hip/hip_fp16.h>

// RNN_14078902797083: 2-layer tanh RNN + FC + softmax, fp32 in/out.
// B=64, T=2048, IN=256, H=512, NCLASS=2.
//
// R13: k-split scan within one WG. Model (R5/R11/R12): scan cost tracks DS
// instrs/CU-step at >=2 waves/SIMD (R11: 264 ~= 3100cyc, 12cyc/instr);
// R12's 4-wave attempt died from zero TLP (1 wave/SIMD). Keep 512 threads
// (8 waves): thread j = (k-half j>>8, row j&255) partial-dots rows r,r+256
// over HALF of h -> 16 uniform b128 h-reads (vs R11's 32). Int partials to
// LDS (exact), combined by thread j for row j, tanh, 1-byte publish.
// DS/CU-step: 168 vs 264. Cost: +1 barrier/step. Per-row scale from
// full-row max via one-time smax exchange; numerics = R11 (absmax 0.0039).

#define BB 64
#define TT 2048
#define IN 256
#define HH 512
#define MM (BB * TT)          // 131072 rows

// workspace layout (bytes)
#define BUF0_OFF 0ull                      // [B][T][H] f32 = 256 MB (xw0 -> h1 -> xw1, in place)
#define WT_OFF   268435456ull              // W^T scratch, 1 MB
#define H2L_OFF  269484032ull              // [B][H] f32 last hidden = 128 KB

__device__ __forceinline__ int sd4(unsigned a, unsigned b, int c) {
#if __has_builtin(__builtin_amdgcn_sdot4)
    return __builtin_amdgcn_sdot4((int)a, (int)b, c, false);
#else
    const int a0 = (int)(char)(a), a1 = (int)(char)(a >> 8);
    const int a2 = (int)(char)(a >> 16), a3 = (int)(char)(a >> 24);
    const int b0 = (int)(char)(b), b1 = (int)(char)(b >> 8);
    const int b2 = (int)(char)(b >> 16), b3 = (int)(char)(b >> 24);
    return c + a0 * b0 + a1 * b1 + a2 * b2 + a3 * b3;
#endif
}

// fast tanh: copysign((1-e)/(1+e), x), e = exp(-2|x|). No overflow; ~2e-6 abs err.
__device__ __forceinline__ float fast_tanh(float x) {
    const float ax = __builtin_fabsf(x);
    const float e  = __expf(-2.f * ax);
    const float r  = (1.f - e) * __builtin_amdgcn_rcpf(1.f + e);
    return __builtin_copysignf(r, x);
}

__device__ __forceinline__ unsigned pkq4(float s, float x0, float x1, float x2, float x3) {
    const int q0 = (int)rintf(x0 * s), q1 = (int)rintf(x1 * s);
    const int q2 = (int)rintf(x2 * s), q3 = (int)rintf(x3 * s);
    return (unsigned)(q0 & 0xFF) | ((unsigned)(q1 & 0xFF) << 8) |
           ((unsigned)(q2 & 0xFF) << 16) | ((unsigned)(q3 & 0xFF) << 24);
}

// -------------------- W transpose: W[512][K] -> WT[K][512] --------------------
__global__ void transpose_w(const float* __restrict__ W, float* __restrict__ WT, int K)
{
    __shared__ float tile[32][33];
    const int k0 = blockIdx.x * 32;
    const int c0 = blockIdx.y * 32;
    const int tx = threadIdx.x & 31;
    const int ty = threadIdx.x >> 5;          // 0..7
    #pragma unroll
    for (int i = ty; i < 32; i += 8)
        tile[i][tx] = W[(size_t)(c0 + i) * K + k0 + tx];   // coalesced along k
    __syncthreads();
    #pragma unroll
    for (int i = ty; i < 32; i += 8)
        WT[(size_t)(k0 + i) * HH + c0 + tx] = tile[tx][i]; // coalesced along c
}

// -------------------- input projection GEMM: out = A @ W^T + (b1+b2) ----------
// A [M][K] (may alias out), WT [K][512], out [M][512]. 32 rows/WG, full N.
// Full-K A staging in LDS BEFORE any write -> in-place safe per 32-row block.
template <int K>
__global__ __launch_bounds__(256, 2)
void gemm_xw(const float* A, const float* __restrict__ WT,
             const float* __restrict__ b1, const float* __restrict__ b2,
             float* out)
{
    extern __shared__ char smem[];
    float* As = (float*)smem;                 // [32][K]
    const int m0 = blockIdx.x * 32;
    const int tid = threadIdx.x;

    const float* Ab = A + (size_t)m0 * K;
    #pragma unroll
    for (int i = 0; i < (32 * K) / 1024; ++i) {
        const int idx = tid * 4 + i * 1024;
        *(float4*)&As[idx] = *(const float4*)&Ab[idx];
    }
    __syncthreads();

    const int tc = tid & 63;                  // col base lane; cols c = tc + 64*cc
    const int r0 = (tid >> 6) * 8;            // 8 rows per thread

    float acc[8][8];
    #pragma unroll
    for (int cc = 0; cc < 8; ++cc) {
        const int c = tc + 64 * cc;
        const float bb = b1[c] + b2[c];
        #pragma unroll
        for (int rr = 0; rr < 8; ++rr) acc[rr][cc] = bb;
    }

    #pragma unroll 2
    for (int k = 0; k < K; k += 4) {
        float4 av4[8];
        #pragma unroll
        for (int rr = 0; rr < 8; ++rr)
            av4[rr] = *(const float4*)&As[(r0 + rr) * K + k];   // wave-uniform: broadcast
        #pragma unroll
        for (int kk = 0; kk < 4; ++kk) {
            float wv[8];
            #pragma unroll
            for (int cc = 0; cc < 8; ++cc)
                wv[cc] = WT[(size_t)(k + kk) * HH + tc + 64 * cc];  // lane-consecutive: coalesced
            #pragma unroll
            for (int rr = 0; rr < 8; ++rr) {
                const float a = ((const float*)&av4[rr])[kk];
                #pragma unroll
                for (int cc = 0; cc < 8; ++cc)
                    acc[rr][cc] = fmaf(a, wv[cc], acc[rr][cc]);
            }
        }
    }

    #pragma unroll
    for (int rr = 0; rr < 8; ++rr) {
        float* orow = out + (size_t)(m0 + r0 + rr) * HH;
        #pragma unroll
        for (int cc = 0; cc < 8; ++cc)
            orow[tc + 64 * cc] = acc[rr][cc];
    }
}

// -------------------- recurrent scan: 512 thr, k-split, int8 dot4 -------------
// Thread j: k-half hf=j>>8, rows r=j&255 and r+256. 128 int8 weight dwords in
// registers. h: 512 int8 in LDS; each wave reads only its k-half (16 uniform
// b128). Int partials -> LDS red[2][512]; thread j combines row j.
template <bool WRITE_SEQ>
__global__ __launch_bounds__(512, 2)
void scan_rnn(const float* xw,                 // [B][T][H]; aliased by hseq when WRITE_SEQ
              const float* __restrict__ Whh,   // [H][H]
              float* hseq)                     // WRITE_SEQ: [B][T][H] (alias of xw); else [B][H]
{
    __shared__ alignas(16) unsigned hq[128];   // 512 int8 h (single buffer; barrier-protected)
    __shared__ int   red[2][512];              // [k-half][row] int partials
    __shared__ float smax[2][512];             // setup: [k-half][row] half-row abs-max

    const int b  = blockIdx.x;
    const int j  = threadIdx.x;                // 0..511
    const int hf = j >> 8;                     // k-half (wave-uniform)
    const int r  = j & 255;                    // first owned row
    const int r2 = r + 256;                    // second owned row
    const int k0 = hf * 256;                   // k-range start (values)

    // ---- setup: half-row maxima -> full-row scales -> quantize weights ----
    const float* wr0 = Whh + (size_t)r  * HH + k0;
    const float* wr1 = Whh + (size_t)r2 * HH + k0;
    float mx0 = 1e-20f, mx1 = 1e-20f;
    #pragma unroll
    for (int c = 0; c < 64; ++c) {
        const float4 f0 = *(const float4*)(wr0 + 4 * c);
        const float4 f1 = *(const float4*)(wr1 + 4 * c);
        mx0 = fmaxf(mx0, fmaxf(fmaxf(__builtin_fabsf(f0.x), __builtin_fabsf(f0.y)),
                               fmaxf(__builtin_fabsf(f0.z), __builtin_fabsf(f0.w))));
        mx1 = fmaxf(mx1, fmaxf(fmaxf(__builtin_fabsf(f1.x), __builtin_fabsf(f1.y)),
                               fmaxf(__builtin_fabsf(f1.z), __builtin_fabsf(f1.w))));
    }
    smax[hf][r]  = mx0;
    smax[hf][r2] = mx1;
    __syncthreads();
    const float inv0   = 127.f / fmaxf(smax[0][r],  smax[1][r]);    // row r scale
    const float inv1   = 127.f / fmaxf(smax[0][r2], smax[1][r2]);   // row r2 scale
    const float scaleJ = fmaxf(smax[0][j], smax[1][j]) / 16129.f;   // combine row j

    unsigned w8a[64], w8b[64];
    #pragma unroll
    for (int c = 0; c < 64; ++c) {
        w8a[c] = pkq4(inv0, wr0[4 * c], wr0[4 * c + 1], wr0[4 * c + 2], wr0[4 * c + 3]);
        w8b[c] = pkq4(inv1, wr1[4 * c], wr1[4 * c + 1], wr1[4 * c + 2], wr1[4 * c + 3]);
    }

    const float* xrow = xw + (size_t)b * TT * HH + j;
    float* srow = WRITE_SEQ ? (hseq + (size_t)b * TT * HH + j) : nullptr;
    float xc = xrow[0], xn = xrow[HH];

    for (int t = 0; t < TT; ++t) {
        // ---- phase 1: partial dots over this wave's k-half ----
        if (t > 0) {
            const uint4* hp = (const uint4*)(hq + hf * 64);   // wave-uniform base
            int a0 = 0, a1 = 0;
            #pragma unroll
            for (int c = 0; c < 16; ++c) {
                const uint4 hb = hp[c];                       // uniform: LDS broadcast
                a0 = sd4(w8a[4 * c + 0], hb.x, a0);
                a1 = sd4(w8b[4 * c + 0], hb.x, a1);
                a0 = sd4(w8a[4 * c + 1], hb.y, a0);
                a1 = sd4(w8b[4 * c + 1], hb.y, a1);
                a0 = sd4(w8a[4 * c + 2], hb.z, a0);
                a1 = sd4(w8b[4 * c + 2], hb.z, a1);
                a0 = sd4(w8a[4 * c + 3], hb.w, a0);
                a1 = sd4(w8b[4 * c + 3], hb.w, a1);
            }
            red[hf][r]  = a0;                                 // lane-consecutive: conflict-free
            red[hf][r2] = a1;
        }
        __syncthreads();

        // ---- phase 2: combine row j, tanh, publish ----
        float z = xc;
        if (t > 0) z += (float)(red[0][j] + red[1][j]) * scaleJ;
        const float h = fast_tanh(z);
        const int q = (int)rintf(fminf(fmaxf(h * 127.f, -127.f), 127.f));
        ((char*)hq)[j] = (char)q;

        if (WRITE_SEQ) {
            srow[(size_t)t * HH] = h;          // in-place over xw[b][t][j]: thread-local element
        } else if (t == TT - 1) {
            hseq[b * HH + j] = h;
        }
        const int t2 = (t + 2 < TT) ? (t + 2) : (TT - 1);
        xc = xn;
        xn = xrow[(size_t)t2 * HH];            // 2-deep prefetch
        __syncthreads();
    }
}

// -------------------- FC + softmax --------------------
__global__ void fc_kernel(const float* __restrict__ h2, const float* __restrict__ w,
                          const float* __restrict__ bvec, float* __restrict__ out)
{
    const int b = threadIdx.x;   // 64 threads
    float z0 = bvec[0], z1 = bvec[1];
    #pragma unroll 4
    for (int k = 0; k < HH; k += 4) {
        float4 h  = *(const float4*)&h2[b * HH + k];
        float4 w0 = *(const float4*)&w[k];
        float4 w1 = *(const float4*)&w[HH + k];
        z0 += h.x * w0.x + h.y * w0.y + h.z * w0.z + h.w * w0.w;
        z1 += h.x * w1.x + h.y * w1.y + h.z * w1.z + h.w * w1.w;
    }
    const float m  = fmaxf(z0, z1);
    const float e0 = expf(z0 - m), e1 = expf(z1 - m);
    const float inv = 1.f / (e0 + e1);
    out[b * 2 + 0] = e0 * inv;
    out[b * 2 + 1] = e1 * inv;
}

extern "C" void kernel_launch(void* const* d_in, const int* in_sizes, int n_in,
                              void* d_out, int out_size, void* d_ws, size_t ws_size,
                              hipStream_t stream)
{
    (void)in_sizes; (void)n_in; (void)out_size; (void)ws_size;
    const float* x    = (const float*)d_in[0];
    const float* Wih0 = (const float*)d_in[1];
    const float* Whh0 = (const float*)d_in[2];
    const float* bih0 = (const float*)d_in[3];
    const float* bhh0 = (const float*)d_in[4];
    const float* Wih1 = (const float*)d_in[5];
    const float* Whh1 = (const float*)d_in[6];
    const float* bih1 = (const float*)d_in[7];
    const float* bhh1 = (const float*)d_in[8];
    const float* fcw  = (const float*)d_in[9];
    const float* fcb  = (const float*)d_in[10];
    float* out = (float*)d_out;

    char* ws = (char*)d_ws;
    float* buf0 = (float*)(ws + BUF0_OFF);
    float* WT   = (float*)(ws + WT_OFF);
    float* h2l  = (float*)(ws + H2L_OFF);

    // ---- layer 0 ----
    transpose_w<<<dim3(IN / 32, HH / 32), dim3(256), 0, stream>>>(Wih0, WT, IN);
    gemm_xw<IN><<<dim3(MM / 32), dim3(256), 32 * IN * 4, stream>>>(x, WT, bih0, bhh0, buf0);
    scan_rnn<true><<<dim3(BB), dim3(512), 0, stream>>>(buf0, Whh0, buf0);

    // ---- layer 1 (WT buffer reused: lifetimes disjoint) ----
    transpose_w<<<dim3(HH / 32, HH / 32), dim3(256), 0, stream>>>(Wih1, WT, HH);
    gemm_xw<HH><<<dim3(MM / 32), dim3(256), 32 * HH * 4, stream>>>(buf0, WT, bih1, bhh1, buf0);
    scan_rnn<false><<<dim3(BB), dim3(512), 0, stream>>>(buf0, Whh1, h2l);

    // ---- FC + softmax ----
    fc_kernel<<<dim3(1), dim3(64), 0, stream>>>(h2l, fcw, fcb, out);
}

// Round 10
// 5314.219 us; speedup vs baseline: 1.8204x; 1.1804x over previous
//
#include <hip/hip_runtime.h>
#include <hip/hip_fp16.h>

// RNN_14078902797083: 2-layer tanh RNN + FC + softmax, fp32 in/out.
// B=64, T=2048, IN=256, H=512, NCLASS=2.
//
// R14: intra-wave k-split scan. R13 showed LDS-reduction + 2nd barrier eat
// the k-split gain (~17cyc/DS-instr effective). New: lane l of wave w takes
// k-half kh=l>>5 of rows R0=w*32+(l&31) and R0+256. h-reads become
// 2-ADDRESS b128 (lanes 0-31: h-low chunk, 32-63: h-high chunk) — per
// R11's own data, b128 cost is lanes x width (~12cyc) regardless of
// address uniformity, so 16 reads/wave cover full h (vs R11's 32).
// Partials -> float with per-(row,half) scale, combined across the lane
// pair via 2x __shfl_xor(32) (ds_bpermute; no LDS red, no 2nd barrier).
// Lane kh=0 finishes R0, kh=1 finishes R1 - symmetric, no divergence.
// DS/CU-step: 152 vs R13's 168+combine-serialization. 1 barrier/step,
// LDS 1KB. Weights: 128 int8 dwords/thread in VGPR/AGPR (R11-proven).

#define BB 64
#define TT 2048
#define IN 256
#define HH 512
#define MM (BB * TT)          // 131072 rows

// workspace layout (bytes)
#define BUF0_OFF 0ull                      // [B][T][H] f32 = 256 MB (xw0 -> h1 -> xw1, in place)
#define WT_OFF   268435456ull              // W^T scratch, 1 MB
#define H2L_OFF  269484032ull              // [B][H] f32 last hidden = 128 KB

__device__ __forceinline__ int sd4(unsigned a, unsigned b, int c) {
#if __has_builtin(__builtin_amdgcn_sdot4)
    return __builtin_amdgcn_sdot4((int)a, (int)b, c, false);
#else
    const int a0 = (int)(char)(a), a1 = (int)(char)(a >> 8);
    const int a2 = (int)(char)(a >> 16), a3 = (int)(char)(a >> 24);
    const int b0 = (int)(char)(b), b1 = (int)(char)(b >> 8);
    const int b2 = (int)(char)(b >> 16), b3 = (int)(char)(b >> 24);
    return c + a0 * b0 + a1 * b1 + a2 * b2 + a3 * b3;
#endif
}

// fast tanh: copysign((1-e)/(1+e), x), e = exp(-2|x|). No overflow; ~2e-6 abs err.
__device__ __forceinline__ float fast_tanh(float x) {
    const float ax = __builtin_fabsf(x);
    const float e  = __expf(-2.f * ax);
    const float r  = (1.f - e) * __builtin_amdgcn_rcpf(1.f + e);
    return __builtin_copysignf(r, x);
}

__device__ __forceinline__ unsigned pkq4(float s, float x0, float x1, float x2, float x3) {
    const int q0 = (int)rintf(x0 * s), q1 = (int)rintf(x1 * s);
    const int q2 = (int)rintf(x2 * s), q3 = (int)rintf(x3 * s);
    return (unsigned)(q0 & 0xFF) | ((unsigned)(q1 & 0xFF) << 8) |
           ((unsigned)(q2 & 0xFF) << 16) | ((unsigned)(q3 & 0xFF) << 24);
}

// -------------------- W transpose: W[512][K] -> WT[K][512] --------------------
__global__ void transpose_w(const float* __restrict__ W, float* __restrict__ WT, int K)
{
    __shared__ float tile[32][33];
    const int k0 = blockIdx.x * 32;
    const int c0 = blockIdx.y * 32;
    const int tx = threadIdx.x & 31;
    const int ty = threadIdx.x >> 5;          // 0..7
    #pragma unroll
    for (int i = ty; i < 32; i += 8)
        tile[i][tx] = W[(size_t)(c0 + i) * K + k0 + tx];   // coalesced along k
    __syncthreads();
    #pragma unroll
    for (int i = ty; i < 32; i += 8)
        WT[(size_t)(k0 + i) * HH + c0 + tx] = tile[tx][i]; // coalesced along c
}

// -------------------- input projection GEMM: out = A @ W^T + (b1+b2) ----------
// A [M][K] (may alias out), WT [K][512], out [M][512]. 32 rows/WG, full N.
// Full-K A staging in LDS BEFORE any write -> in-place safe per 32-row block.
template <int K>
__global__ __launch_bounds__(256, 2)
void gemm_xw(const float* A, const float* __restrict__ WT,
             const float* __restrict__ b1, const float* __restrict__ b2,
             float* out)
{
    extern __shared__ char smem[];
    float* As = (float*)smem;                 // [32][K]
    const int m0 = blockIdx.x * 32;
    const int tid = threadIdx.x;

    const float* Ab = A + (size_t)m0 * K;
    #pragma unroll
    for (int i = 0; i < (32 * K) / 1024; ++i) {
        const int idx = tid * 4 + i * 1024;
        *(float4*)&As[idx] = *(const float4*)&Ab[idx];
    }
    __syncthreads();

    const int tc = tid & 63;                  // col base lane; cols c = tc + 64*cc
    const int r0 = (tid >> 6) * 8;            // 8 rows per thread

    float acc[8][8];
    #pragma unroll
    for (int cc = 0; cc < 8; ++cc) {
        const int c = tc + 64 * cc;
        const float bb = b1[c] + b2[c];
        #pragma unroll
        for (int rr = 0; rr < 8; ++rr) acc[rr][cc] = bb;
    }

    #pragma unroll 2
    for (int k = 0; k < K; k += 4) {
        float4 av4[8];
        #pragma unroll
        for (int rr = 0; rr < 8; ++rr)
            av4[rr] = *(const float4*)&As[(r0 + rr) * K + k];   // wave-uniform: broadcast
        #pragma unroll
        for (int kk = 0; kk < 4; ++kk) {
            float wv[8];
            #pragma unroll
            for (int cc = 0; cc < 8; ++cc)
                wv[cc] = WT[(size_t)(k + kk) * HH + tc + 64 * cc];  // lane-consecutive: coalesced
            #pragma unroll
            for (int rr = 0; rr < 8; ++rr) {
                const float a = ((const float*)&av4[rr])[kk];
                #pragma unroll
                for (int cc = 0; cc < 8; ++cc)
                    acc[rr][cc] = fmaf(a, wv[cc], acc[rr][cc]);
            }
        }
    }

    #pragma unroll
    for (int rr = 0; rr < 8; ++rr) {
        float* orow = out + (size_t)(m0 + r0 + rr) * HH;
        #pragma unroll
        for (int cc = 0; cc < 8; ++cc)
            orow[tc + 64 * cc] = acc[rr][cc];
    }
}

// -------------------- recurrent scan: 512 thr, intra-wave k-split, int8 -------
// Lane l of wave w: k-half kh=l>>5, rows R0=w*32+(l&31), R1=R0+256.
// h: 512 int8 in LDS (dbuf); wave reads 16x 2-address b128 (full h).
// Combine across lane pair via __shfl_xor(32); lane kh finishes row R_kh.
template <bool WRITE_SEQ>
__global__ __launch_bounds__(512, 2)
void scan_rnn(const float* xw,                 // [B][T][H]; aliased by hseq when WRITE_SEQ
              const float* __restrict__ Whh,   // [H][H]
              float* hseq)                     // WRITE_SEQ: [B][T][H] (alias of xw); else [B][H]
{
    __shared__ alignas(16) unsigned hq[2][128];   // [parity][512 int8, row-order]

    const int b   = blockIdx.x;
    const int tid = threadIdx.x;               // 0..511
    const int w   = tid >> 6;                  // wave 0..7
    const int l   = tid & 63;                  // lane
    const int kh  = l >> 5;                    // k-half of this lane
    const int rr  = l & 31;
    const int R0  = w * 32 + rr;               // row pair
    const int R1  = R0 + 256;
    const int myrow = kh ? R1 : R0;            // row this lane finishes
    const int kb  = kh * 256;                  // k-range start (values)

    // ---- setup: quantize rows R0,R1 over cols [kb, kb+256) -> 128 dwords ----
    const float* wr0 = Whh + (size_t)R0 * HH + kb;
    const float* wr1 = Whh + (size_t)R1 * HH + kb;
    float mx0 = 1e-20f, mx1 = 1e-20f;
    #pragma unroll
    for (int c = 0; c < 64; ++c) {
        const float4 f0 = *(const float4*)(wr0 + 4 * c);
        const float4 f1 = *(const float4*)(wr1 + 4 * c);
        mx0 = fmaxf(mx0, fmaxf(fmaxf(__builtin_fabsf(f0.x), __builtin_fabsf(f0.y)),
                               fmaxf(__builtin_fabsf(f0.z), __builtin_fabsf(f0.w))));
        mx1 = fmaxf(mx1, fmaxf(fmaxf(__builtin_fabsf(f1.x), __builtin_fabsf(f1.y)),
                               fmaxf(__builtin_fabsf(f1.z), __builtin_fabsf(f1.w))));
    }
    const float inv0 = 127.f / mx0, scale0 = mx0 / 16129.f;   // (row,half)-local scales
    const float inv1 = 127.f / mx1, scale1 = mx1 / 16129.f;
    unsigned w8a[64], w8b[64];
    #pragma unroll
    for (int c = 0; c < 64; ++c) {
        w8a[c] = pkq4(inv0, wr0[4 * c], wr0[4 * c + 1], wr0[4 * c + 2], wr0[4 * c + 3]);
        w8b[c] = pkq4(inv1, wr1[4 * c], wr1[4 * c + 1], wr1[4 * c + 2], wr1[4 * c + 3]);
    }

    const float* xrow = xw + (size_t)b * TT * HH + myrow;
    float* srow = WRITE_SEQ ? (hseq + (size_t)b * TT * HH + myrow) : nullptr;
    float xc = xrow[0], xn = xrow[HH];

    for (int t = 0; t < TT; ++t) {
        const int t2 = (t + 2 < TT) ? (t + 2) : (TT - 1);
        const float xn2 = xrow[(size_t)t2 * HH];         // 2-deep prefetch

        float z = xc;
        if (t > 0) {
            // 2-address reads: this lane reads its k-half's chunks
            const unsigned* hp = hq[(t & 1) ^ 1] + kh * 64;
            int a0 = 0, a1 = 0;
            #pragma unroll
            for (int c = 0; c < 16; ++c) {
                const uint4 hb = *(const uint4*)(hp + 4 * c);
                a0 = sd4(w8a[4 * c + 0], hb.x, a0);
                a1 = sd4(w8b[4 * c + 0], hb.x, a1);
                a0 = sd4(w8a[4 * c + 1], hb.y, a0);
                a1 = sd4(w8b[4 * c + 1], hb.y, a1);
                a0 = sd4(w8a[4 * c + 2], hb.z, a0);
                a1 = sd4(w8b[4 * c + 2], hb.z, a1);
                a0 = sd4(w8a[4 * c + 3], hb.w, a0);
                a1 = sd4(w8b[4 * c + 3], hb.w, a1);
            }
            float f0 = (float)a0 * scale0;               // partial(R0, my half)
            float f1 = (float)a1 * scale1;               // partial(R1, my half)
            f0 += __shfl_xor(f0, 32, 64);                // + partner half (other scale)
            f1 += __shfl_xor(f1, 32, 64);
            z += kh ? f1 : f0;                           // full dot of myrow
        }
        const float h = fast_tanh(z);

        // publish h_t (row-order byte) into parity t&1
        const int q = (int)rintf(fminf(fmaxf(h * 127.f, -127.f), 127.f));
        ((char*)hq[t & 1])[myrow] = (char)q;

        if (WRITE_SEQ) {
            srow[(size_t)t * HH] = h;          // in-place over xw[b][t][myrow]: own element
        } else if (t == TT - 1) {
            hseq[b * HH + myrow] = h;
        }
        xc = xn;
        xn = xn2;
        __syncthreads();
    }
}

// -------------------- FC + softmax --------------------
__global__ void fc_kernel(const float* __restrict__ h2, const float* __restrict__ w,
                          const float* __restrict__ bvec, float* __restrict__ out)
{
    const int b = threadIdx.x;   // 64 threads
    float z0 = bvec[0], z1 = bvec[1];
    #pragma unroll 4
    for (int k = 0; k < HH; k += 4) {
        float4 h  = *(const float4*)&h2[b * HH + k];
        float4 w0 = *(const float4*)&w[k];
        float4 w1 = *(const float4*)&w[HH + k];
        z0 += h.x * w0.x + h.y * w0.y + h.z * w0.z + h.w * w0.w;
        z1 += h.x * w1.x + h.y * w1.y + h.z * w1.z + h.w * w1.w;
    }
    const float m  = fmaxf(z0, z1);
    const float e0 = expf(z0 - m), e1 = expf(z1 - m);
    const float inv = 1.f / (e0 + e1);
    out[b * 2 + 0] = e0 * inv;
    out[b * 2 + 1] = e1 * inv;
}

extern "C" void kernel_launch(void* const* d_in, const int* in_sizes, int n_in,
                              void* d_out, int out_size, void* d_ws, size_t ws_size,
                              hipStream_t stream)
{
    (void)in_sizes; (void)n_in; (void)out_size; (void)ws_size;
    const float* x    = (const float*)d_in[0];
    const float* Wih0 = (const float*)d_in[1];
    const float* Whh0 = (const float*)d_in[2];
    const float* bih0 = (const float*)d_in[3];
    const float* bhh0 = (const float*)d_in[4];
    const float* Wih1 = (const float*)d_in[5];
    const float* Whh1 = (const float*)d_in[6];
    const float* bih1 = (const float*)d_in[7];
    const float* bhh1 = (const float*)d_in[8];
    const float* fcw  = (const float*)d_in[9];
    const float* fcb  = (const float*)d_in[10];
    float* out = (float*)d_out;

    char* ws = (char*)d_ws;
    float* buf0 = (float*)(ws + BUF0_OFF);
    float* WT   = (float*)(ws + WT_OFF);
    float* h2l  = (float*)(ws + H2L_OFF);

    // ---- layer 0 ----
    transpose_w<<<dim3(IN / 32, HH / 32), dim3(256), 0, stream>>>(Wih0, WT, IN);
    gemm_xw<IN><<<dim3(MM / 32), dim3(256), 32 * IN * 4, stream>>>(x, WT, bih0, bhh0, buf0);
    scan_rnn<true><<<dim3(BB), dim3(512), 0, stream>>>(buf0, Whh0, buf0);

    // ---- layer 1 (WT buffer reused: lifetimes disjoint) ----
    transpose_w<<<dim3(HH / 32, HH / 32), dim3(256), 0, stream>>>(Wih1, WT, HH);
    gemm_xw<HH><<<dim3(MM / 32), dim3(256), 32 * HH * 4, stream>>>(buf0, WT, bih1, bhh1, buf0);
    scan_rnn<false><<<dim3(BB), dim3(512), 0, stream>>>(buf0, Whh1, h2l);

    // ---- FC + softmax ----
    fc_kernel<<<dim3(1), dim3(64), 0, stream>>>(h2l, fcw, fcb, out);
}

// Round 11
// 4919.062 us; speedup vs baseline: 1.9666x; 1.0803x over previous
//
#include <hip/hip_runtime.h>
#include <hip/hip_fp16.h>

// RNN_14078902797083: 2-layer tanh RNN + FC + softmax, fp32 in/out.
// B=64, T=2048, IN=256, H=512, NCLASS=2.
//
// R15: k-quarter intra-wave split. R14 validated: multi-address b128 costs
// ~12cyc like uniform, shfl-combine beats LDS reduction. Now lane l of wave
// w takes quarter q=l>>4 of FOUR rows rbase+128i (rbase=w*16+(l&15)):
// 8x 4-address b128 h-reads/wave (vs 16), 128 sdot4 (unchanged), 2-round
// shfl-xor butterfly (xor16, xor32; 3 bpermutes) leaves lane q with the
// full dot of row rbase+128q. DS/wave: 8+3+1=12 -> 96/CU-step ~1150cyc
// + barrier ~450 => ~1600-1700 cyc/step vs R14's 2420. Per-(row,quarter)
// scales applied before the float butterfly (R14-proven numerics).

#define BB 64
#define TT 2048
#define IN 256
#define HH 512
#define MM (BB * TT)          // 131072 rows

// workspace layout (bytes)
#define BUF0_OFF 0ull                      // [B][T][H] f32 = 256 MB (xw0 -> h1 -> xw1, in place)
#define WT_OFF   268435456ull              // W^T scratch, 1 MB
#define H2L_OFF  269484032ull              // [B][H] f32 last hidden = 128 KB

__device__ __forceinline__ int sd4(unsigned a, unsigned b, int c) {
#if __has_builtin(__builtin_amdgcn_sdot4)
    return __builtin_amdgcn_sdot4((int)a, (int)b, c, false);
#else
    const int a0 = (int)(char)(a), a1 = (int)(char)(a >> 8);
    const int a2 = (int)(char)(a >> 16), a3 = (int)(char)(a >> 24);
    const int b0 = (int)(char)(b), b1 = (int)(char)(b >> 8);
    const int b2 = (int)(char)(b >> 16), b3 = (int)(char)(b >> 24);
    return c + a0 * b0 + a1 * b1 + a2 * b2 + a3 * b3;
#endif
}

// fast tanh: copysign((1-e)/(1+e), x), e = exp(-2|x|). No overflow; ~2e-6 abs err.
__device__ __forceinline__ float fast_tanh(float x) {
    const float ax = __builtin_fabsf(x);
    const float e  = __expf(-2.f * ax);
    const float r  = (1.f - e) * __builtin_amdgcn_rcpf(1.f + e);
    return __builtin_copysignf(r, x);
}

__device__ __forceinline__ unsigned pkq4(float s, float x0, float x1, float x2, float x3) {
    const int q0 = (int)rintf(x0 * s), q1 = (int)rintf(x1 * s);
    const int q2 = (int)rintf(x2 * s), q3 = (int)rintf(x3 * s);
    return (unsigned)(q0 & 0xFF) | ((unsigned)(q1 & 0xFF) << 8) |
           ((unsigned)(q2 & 0xFF) << 16) | ((unsigned)(q3 & 0xFF) << 24);
}

// -------------------- W transpose: W[512][K] -> WT[K][512] --------------------
__global__ void transpose_w(const float* __restrict__ W, float* __restrict__ WT, int K)
{
    __shared__ float tile[32][33];
    const int k0 = blockIdx.x * 32;
    const int c0 = blockIdx.y * 32;
    const int tx = threadIdx.x & 31;
    const int ty = threadIdx.x >> 5;          // 0..7
    #pragma unroll
    for (int i = ty; i < 32; i += 8)
        tile[i][tx] = W[(size_t)(c0 + i) * K + k0 + tx];   // coalesced along k
    __syncthreads();
    #pragma unroll
    for (int i = ty; i < 32; i += 8)
        WT[(size_t)(k0 + i) * HH + c0 + tx] = tile[tx][i]; // coalesced along c
}

// -------------------- input projection GEMM: out = A @ W^T + (b1+b2) ----------
// A [M][K] (may alias out), WT [K][512], out [M][512]. 32 rows/WG, full N.
// Full-K A staging in LDS BEFORE any write -> in-place safe per 32-row block.
template <int K>
__global__ __launch_bounds__(256, 2)
void gemm_xw(const float* A, const float* __restrict__ WT,
             const float* __restrict__ b1, const float* __restrict__ b2,
             float* out)
{
    extern __shared__ char smem[];
    float* As = (float*)smem;                 // [32][K]
    const int m0 = blockIdx.x * 32;
    const int tid = threadIdx.x;

    const float* Ab = A + (size_t)m0 * K;
    #pragma unroll
    for (int i = 0; i < (32 * K) / 1024; ++i) {
        const int idx = tid * 4 + i * 1024;
        *(float4*)&As[idx] = *(const float4*)&Ab[idx];
    }
    __syncthreads();

    const int tc = tid & 63;                  // col base lane; cols c = tc + 64*cc
    const int r0 = (tid >> 6) * 8;            // 8 rows per thread

    float acc[8][8];
    #pragma unroll
    for (int cc = 0; cc < 8; ++cc) {
        const int c = tc + 64 * cc;
        const float bb = b1[c] + b2[c];
        #pragma unroll
        for (int rr = 0; rr < 8; ++rr) acc[rr][cc] = bb;
    }

    #pragma unroll 2
    for (int k = 0; k < K; k += 4) {
        float4 av4[8];
        #pragma unroll
        for (int rr = 0; rr < 8; ++rr)
            av4[rr] = *(const float4*)&As[(r0 + rr) * K + k];   // wave-uniform: broadcast
        #pragma unroll
        for (int kk = 0; kk < 4; ++kk) {
            float wv[8];
            #pragma unroll
            for (int cc = 0; cc < 8; ++cc)
                wv[cc] = WT[(size_t)(k + kk) * HH + tc + 64 * cc];  // lane-consecutive: coalesced
            #pragma unroll
            for (int rr = 0; rr < 8; ++rr) {
                const float a = ((const float*)&av4[rr])[kk];
                #pragma unroll
                for (int cc = 0; cc < 8; ++cc)
                    acc[rr][cc] = fmaf(a, wv[cc], acc[rr][cc]);
            }
        }
    }

    #pragma unroll
    for (int rr = 0; rr < 8; ++rr) {
        float* orow = out + (size_t)(m0 + r0 + rr) * HH;
        #pragma unroll
        for (int cc = 0; cc < 8; ++cc)
            orow[tc + 64 * cc] = acc[rr][cc];
    }
}

// -------------------- recurrent scan: 512 thr, k-quarter split, int8 ----------
// Lane l of wave w: quarter q=l>>4, rows rbase+128i (rbase=w*16+(l&15), i=0..3).
// 8x 4-address b128 h-reads; 128 sdot4; 2-round shfl-xor butterfly; lane q
// finishes row rbase+128q. One barrier/step, LDS 1KB dbuf.
template <bool WRITE_SEQ>
__global__ __launch_bounds__(512, 2)
void scan_rnn(const float* xw,                 // [B][T][H]; aliased by hseq when WRITE_SEQ
              const float* __restrict__ Whh,   // [H][H]
              float* hseq)                     // WRITE_SEQ: [B][T][H] (alias of xw); else [B][H]
{
    __shared__ alignas(16) unsigned hq[2][128];   // [parity][512 int8, row-order]

    const int b     = blockIdx.x;
    const int tid   = threadIdx.x;             // 0..511
    const int w     = tid >> 6;                // wave 0..7
    const int l     = tid & 63;                // lane
    const int q     = l >> 4;                  // k-quarter 0..3
    const int rr    = l & 15;
    const int rbase = w * 16 + rr;             // row i = rbase + 128*i
    const int myrow = rbase + 128 * q;         // row this lane finishes
    const int kb    = q * 128;                 // k-range [kb, kb+128)

    // ---- setup: quantize 4 rows over my k-quarter -> 4x32 dwords ----
    unsigned w8[4][32];
    float scl[4];
    #pragma unroll
    for (int i = 0; i < 4; ++i) {
        const float* wr = Whh + (size_t)(rbase + 128 * i) * HH + kb;
        float mx = 1e-20f;
        #pragma unroll
        for (int c = 0; c < 32; ++c) {
            const float4 f = *(const float4*)(wr + 4 * c);
            mx = fmaxf(mx, fmaxf(fmaxf(__builtin_fabsf(f.x), __builtin_fabsf(f.y)),
                                 fmaxf(__builtin_fabsf(f.z), __builtin_fabsf(f.w))));
        }
        const float inv = 127.f / mx;
        scl[i] = mx / 16129.f;                 // (mx/127)/127
        #pragma unroll
        for (int c = 0; c < 32; ++c) {
            const float4 f = *(const float4*)(wr + 4 * c);
            w8[i][c] = pkq4(inv, f.x, f.y, f.z, f.w);
        }
    }

    const float* xrow = xw + (size_t)b * TT * HH + myrow;
    float* srow = WRITE_SEQ ? (hseq + (size_t)b * TT * HH + myrow) : nullptr;
    float xc = xrow[0], xn = xrow[HH];

    for (int t = 0; t < TT; ++t) {
        const int t2 = (t + 2 < TT) ? (t + 2) : (TT - 1);
        const float xn2 = xrow[(size_t)t2 * HH];         // 2-deep prefetch

        float z = xc;
        if (t > 0) {
            // 4-address reads: each 16-lane group reads its quarter's chunks
            const unsigned* hp = hq[(t & 1) ^ 1] + q * 32;
            int a0 = 0, a1 = 0, a2 = 0, a3 = 0;
            #pragma unroll
            for (int c = 0; c < 8; ++c) {
                const uint4 hb = *(const uint4*)(hp + 4 * c);
                a0 = sd4(w8[0][4 * c + 0], hb.x, a0);
                a1 = sd4(w8[1][4 * c + 0], hb.x, a1);
                a2 = sd4(w8[2][4 * c + 0], hb.x, a2);
                a3 = sd4(w8[3][4 * c + 0], hb.x, a3);
                a0 = sd4(w8[0][4 * c + 1], hb.y, a0);
                a1 = sd4(w8[1][4 * c + 1], hb.y, a1);
                a2 = sd4(w8[2][4 * c + 1], hb.y, a2);
                a3 = sd4(w8[3][4 * c + 1], hb.y, a3);
                a0 = sd4(w8[0][4 * c + 2], hb.z, a0);
                a1 = sd4(w8[1][4 * c + 2], hb.z, a1);
                a2 = sd4(w8[2][4 * c + 2], hb.z, a2);
                a3 = sd4(w8[3][4 * c + 2], hb.z, a3);
                a0 = sd4(w8[0][4 * c + 3], hb.w, a0);
                a1 = sd4(w8[1][4 * c + 3], hb.w, a1);
                a2 = sd4(w8[2][4 * c + 3], hb.w, a2);
                a3 = sd4(w8[3][4 * c + 3], hb.w, a3);
            }
            const float f0 = (float)a0 * scl[0];
            const float f1 = (float)a1 * scl[1];
            const float f2 = (float)a2 * scl[2];
            const float f3 = (float)a3 * scl[3];
            // round 1 (xor 16, quarter bit0): keep rows with i&1 == q&1
            const int aa = q & 1;
            const float sendL = aa ? f0 : f1;            // row the partner keeps (low pair)
            const float ownL  = aa ? f1 : f0;
            const float sendH = aa ? f2 : f3;            // high pair
            const float ownH  = aa ? f3 : f2;
            const float keepL = ownL + __shfl_xor(sendL, 16, 64);   // row aa
            const float keepH = ownH + __shfl_xor(sendH, 16, 64);   // row aa+2
            // round 2 (xor 32, quarter bit1): keep row aa + 2*(q>>1) == q
            const int bb2 = q >> 1;
            const float send2 = bb2 ? keepL : keepH;
            const float own2  = bb2 ? keepH : keepL;
            z += own2 + __shfl_xor(send2, 32, 64);
        }
        const float h = fast_tanh(z);

        // publish h_t (row-order byte) into parity t&1
        const int qv = (int)rintf(fminf(fmaxf(h * 127.f, -127.f), 127.f));
        ((char*)hq[t & 1])[myrow] = (char)qv;

        if (WRITE_SEQ) {
            srow[(size_t)t * HH] = h;          // in-place over xw[b][t][myrow]: own element
        } else if (t == TT - 1) {
            hseq[b * HH + myrow] = h;
        }
        xc = xn;
        xn = xn2;
        __syncthreads();
    }
}

// -------------------- FC + softmax --------------------
__global__ void fc_kernel(const float* __restrict__ h2, const float* __restrict__ w,
                          const float* __restrict__ bvec, float* __restrict__ out)
{
    const int b = threadIdx.x;   // 64 threads
    float z0 = bvec[0], z1 = bvec[1];
    #pragma unroll 4
    for (int k = 0; k < HH; k += 4) {
        float4 h  = *(const float4*)&h2[b * HH + k];
        float4 w0 = *(const float4*)&w[k];
        float4 w1 = *(const float4*)&w[HH + k];
        z0 += h.x * w0.x + h.y * w0.y + h.z * w0.z + h.w * w0.w;
        z1 += h.x * w1.x + h.y * w1.y + h.z * w1.z + h.w * w1.w;
    }
    const float m  = fmaxf(z0, z1);
    const float e0 = expf(z0 - m), e1 = expf(z1 - m);
    const float inv = 1.f / (e0 + e1);
    out[b * 2 + 0] = e0 * inv;
    out[b * 2 + 1] = e1 * inv;
}

extern "C" void kernel_launch(void* const* d_in, const int* in_sizes, int n_in,
                              void* d_out, int out_size, void* d_ws, size_t ws_size,
                              hipStream_t stream)
{
    (void)in_sizes; (void)n_in; (void)out_size; (void)ws_size;
    const float* x    = (const float*)d_in[0];
    const float* Wih0 = (const float*)d_in[1];
    const float* Whh0 = (const float*)d_in[2];
    const float* bih0 = (const float*)d_in[3];
    const float* bhh0 = (const float*)d_in[4];
    const float* Wih1 = (const float*)d_in[5];
    const float* Whh1 = (const float*)d_in[6];
    const float* bih1 = (const float*)d_in[7];
    const float* bhh1 = (const float*)d_in[8];
    const float* fcw  = (const float*)d_in[9];
    const float* fcb  = (const float*)d_in[10];
    float* out = (float*)d_out;

    char* ws = (char*)d_ws;
    float* buf0 = (float*)(ws + BUF0_OFF);
    float* WT   = (float*)(ws + WT_OFF);
    float* h2l  = (float*)(ws + H2L_OFF);

    // ---- layer 0 ----
    transpose_w<<<dim3(IN / 32, HH / 32), dim3(256), 0, stream>>>(Wih0, WT, IN);
    gemm_xw<IN><<<dim3(MM / 32), dim3(256), 32 * IN * 4, stream>>>(x, WT, bih0, bhh0, buf0);
    scan_rnn<true><<<dim3(BB), dim3(512), 0, stream>>>(buf0, Whh0, buf0);

    // ---- layer 1 (WT buffer reused: lifetimes disjoint) ----
    transpose_w<<<dim3(HH / 32, HH / 32), dim3(256), 0, stream>>>(Wih1, WT, HH);
    gemm_xw<HH><<<dim3(MM / 32), dim3(256), 32 * HH * 4, stream>>>(buf0, WT, bih1, bhh1, buf0);
    scan_rnn<false><<<dim3(BB), dim3(512), 0, stream>>>(buf0, Whh1, h2l);

    // ---- FC + softmax ----
    fc_kernel<<<dim3(1), dim3(64), 0, stream>>>(h2l, fcw, fcb, out);
}

// Round 12
// 3192.640 us; speedup vs baseline: 3.0301x; 1.5408x over previous
//
#include <hip/hip_runtime.h>
#include <hip/hip_fp16.h>

// RNN_14078902797083: 2-layer tanh RNN + FC + softmax, fp32 in/out.
// B=64, T=2048, IN=256, H=512, NCLASS=2.
//
// R16: chunked layer pipeline. R15's scan fit: cyc/step ~ 1530 + 48*DS_instr
// -> base-dominated; the macro win is that scan0 (64 CUs), gemm1, scan1 ran
// SERIALLY. Now one 256-block kernel (128KB LDS/WG forces 1 WG/CU -> all
// blocks resident, DAG deadlock-free): blocks 0-63 scan0 (R15 verbatim +
// per-64-step chunk tag: threadfence + agent-release store), 64-191
// persistent gemm1 (16 tiles each; tile = (batch, chunk) = 64x512 fp32
// in-place, polls scan0 tags), 192-255 scan1 (poll + chunk-local prefetch;
// final h2 -> buf0 tail). Poll = 1 thread spins w/ s_sleep + barrier + all-
// thread acquire load (R4 lesson: tiny poll footprint). gemm0/transposes
// stay serial pre-kernels. Workspace: buf 256MB + WT 1MB + tags 16KB
// (within proven 269.6MB; H2L dropped -> h2 lives in buf0[b][T-1][:]).

#define BB 64
#define TT 2048
#define IN 256
#define HH 512
#define MM (BB * TT)          // 131072 rows
#define CHUNK 64
#define NCHUNK (TT / CHUNK)   // 32

// workspace layout (bytes)
#define BUF0_OFF 0ull                      // [B][T][H] f32 = 256 MB (xw0 -> h1 -> xw1 -> h2last)
#define WT_OFF   268435456ull              // W^T scratch, 1 MB (WT0 then WT1, stream-ordered)
#define TAGS_OFF 269484032ull              // 4096 u32 = 16 KB (h1done[2048], xw1done[2048])

#define AGENT __HIP_MEMORY_SCOPE_AGENT

__device__ __forceinline__ int sd4(unsigned a, unsigned b, int c) {
#if __has_builtin(__builtin_amdgcn_sdot4)
    return __builtin_amdgcn_sdot4((int)a, (int)b, c, false);
#else
    const int a0 = (int)(char)(a), a1 = (int)(char)(a >> 8);
    const int a2 = (int)(char)(a >> 16), a3 = (int)(char)(a >> 24);
    const int b0 = (int)(char)(b), b1 = (int)(char)(b >> 8);
    const int b2 = (int)(char)(b >> 16), b3 = (int)(char)(b >> 24);
    return c + a0 * b0 + a1 * b1 + a2 * b2 + a3 * b3;
#endif
}

// fast tanh: copysign((1-e)/(1+e), x), e = exp(-2|x|). No overflow; ~2e-6 abs err.
__device__ __forceinline__ float fast_tanh(float x) {
    const float ax = __builtin_fabsf(x);
    const float e  = __expf(-2.f * ax);
    const float r  = (1.f - e) * __builtin_amdgcn_rcpf(1.f + e);
    return __builtin_copysignf(r, x);
}

__device__ __forceinline__ unsigned pkq4(float s, float x0, float x1, float x2, float x3) {
    const int q0 = (int)rintf(x0 * s), q1 = (int)rintf(x1 * s);
    const int q2 = (int)rintf(x2 * s), q3 = (int)rintf(x3 * s);
    return (unsigned)(q0 & 0xFF) | ((unsigned)(q1 & 0xFF) << 8) |
           ((unsigned)(q2 & 0xFF) << 16) | ((unsigned)(q3 & 0xFF) << 24);
}

// -------------------- zero tags --------------------
__global__ void zero_u32(unsigned* a, int n)
{
    int i = blockIdx.x * blockDim.x + threadIdx.x;
    if (i < n) a[i] = 0u;
}

// -------------------- W transpose: W[512][K] -> WT[K][512] --------------------
__global__ void transpose_w(const float* __restrict__ W, float* __restrict__ WT, int K)
{
    __shared__ float tile[32][33];
    const int k0 = blockIdx.x * 32;
    const int c0 = blockIdx.y * 32;
    const int tx = threadIdx.x & 31;
    const int ty = threadIdx.x >> 5;          // 0..7
    #pragma unroll
    for (int i = ty; i < 32; i += 8)
        tile[i][tx] = W[(size_t)(c0 + i) * K + k0 + tx];   // coalesced along k
    __syncthreads();
    #pragma unroll
    for (int i = ty; i < 32; i += 8)
        WT[(size_t)(k0 + i) * HH + c0 + tx] = tile[tx][i]; // coalesced along c
}

// -------------------- input projection GEMM (layer 0, serial pre-kernel) -----
template <int K>
__global__ __launch_bounds__(256, 2)
void gemm_xw(const float* A, const float* __restrict__ WT,
             const float* __restrict__ b1, const float* __restrict__ b2,
             float* out)
{
    extern __shared__ char smem[];
    float* As = (float*)smem;                 // [32][K]
    const int m0 = blockIdx.x * 32;
    const int tid = threadIdx.x;

    const float* Ab = A + (size_t)m0 * K;
    #pragma unroll
    for (int i = 0; i < (32 * K) / 1024; ++i) {
        const int idx = tid * 4 + i * 1024;
        *(float4*)&As[idx] = *(const float4*)&Ab[idx];
    }
    __syncthreads();

    const int tc = tid & 63;
    const int r0 = (tid >> 6) * 8;

    float acc[8][8];
    #pragma unroll
    for (int cc = 0; cc < 8; ++cc) {
        const int c = tc + 64 * cc;
        const float bb = b1[c] + b2[c];
        #pragma unroll
        for (int rr = 0; rr < 8; ++rr) acc[rr][cc] = bb;
    }

    #pragma unroll 2
    for (int k = 0; k < K; k += 4) {
        float4 av4[8];
        #pragma unroll
        for (int rr = 0; rr < 8; ++rr)
            av4[rr] = *(const float4*)&As[(r0 + rr) * K + k];
        #pragma unroll
        for (int kk = 0; kk < 4; ++kk) {
            float wv[8];
            #pragma unroll
            for (int cc = 0; cc < 8; ++cc)
                wv[cc] = WT[(size_t)(k + kk) * HH + tc + 64 * cc];
            #pragma unroll
            for (int rr = 0; rr < 8; ++rr) {
                const float a = ((const float*)&av4[rr])[kk];
                #pragma unroll
                for (int cc = 0; cc < 8; ++cc)
                    acc[rr][cc] = fmaf(a, wv[cc], acc[rr][cc]);
            }
        }
    }

    #pragma unroll
    for (int rr = 0; rr < 8; ++rr) {
        float* orow = out + (size_t)(m0 + r0 + rr) * HH;
        #pragma unroll
        for (int cc = 0; cc < 8; ++cc)
            orow[tc + 64 * cc] = acc[rr][cc];
    }
}

// ==================== pipeline roles ====================

// scan role (R15 k-quarter split, int8 dot4). L0: no poll, streams prefetch,
// writes full h sequence in place, releases h1done per chunk. !L0: polls
// xw1done per chunk, chunk-local prefetch, writes only final h2 in place.
template <bool L0>
__device__ __forceinline__ void scan_role(
    float* buf, const float* __restrict__ Whh, int b, char* smem,
    unsigned* tag_out, const unsigned* tag_in)
{
    unsigned* hq = (unsigned*)smem;            // [2][128] dwords = 512 int8 x2

    const int tid   = threadIdx.x;             // 0..511
    const int w     = tid >> 6;
    const int l     = tid & 63;
    const int q     = l >> 4;                  // k-quarter
    const int rr    = l & 15;
    const int rbase = w * 16 + rr;
    const int myrow = rbase + 128 * q;
    const int kb    = q * 128;

    // setup: quantize 4 rows over my k-quarter -> 4x32 dwords
    unsigned w8[4][32];
    float scl[4];
    #pragma unroll
    for (int i = 0; i < 4; ++i) {
        const float* wr = Whh + (size_t)(rbase + 128 * i) * HH + kb;
        float mx = 1e-20f;
        #pragma unroll
        for (int c = 0; c < 32; ++c) {
            const float4 f = *(const float4*)(wr + 4 * c);
            mx = fmaxf(mx, fmaxf(fmaxf(__builtin_fabsf(f.x), __builtin_fabsf(f.y)),
                                 fmaxf(__builtin_fabsf(f.z), __builtin_fabsf(f.w))));
        }
        const float inv = 127.f / mx;
        scl[i] = mx / 16129.f;
        #pragma unroll
        for (int c = 0; c < 32; ++c) {
            const float4 f = *(const float4*)(wr + 4 * c);
            w8[i][c] = pkq4(inv, f.x, f.y, f.z, f.w);
        }
    }

    float* xrow = buf + (size_t)b * TT * HH + myrow;
    float xc = 0.f, xn = 0.f;
    if (L0) { xc = xrow[0]; xn = xrow[HH]; }

    for (int c = 0; c < NCHUNK; ++c) {
        const int t0 = c * CHUNK;
        if (!L0) {
            if (tid == 0) {
                const unsigned* tp = tag_in + b * NCHUNK + c;
                while (__hip_atomic_load(tp, __ATOMIC_ACQUIRE, AGENT) == 0u)
                    __builtin_amdgcn_s_sleep(8);
            }
            __syncthreads();
            (void)__hip_atomic_load(tag_in + b * NCHUNK + c, __ATOMIC_ACQUIRE, AGENT);
            xc = xrow[(size_t)t0 * HH];
            xn = xrow[(size_t)(t0 + 1) * HH];
        }
        for (int tt = 0; tt < CHUNK; ++tt) {
            const int t = t0 + tt;
            const int t2 = L0 ? ((t + 2 < TT) ? (t + 2) : (TT - 1))
                              : ((tt + 2 < CHUNK) ? (t + 2) : (t0 + CHUNK - 1));
            const float xn2 = xrow[(size_t)t2 * HH];

            float z = xc;
            if (t > 0) {
                const unsigned* hp = hq + ((t & 1) ^ 1) * 128 + q * 32;
                int a0 = 0, a1 = 0, a2 = 0, a3 = 0;
                #pragma unroll
                for (int cc = 0; cc < 8; ++cc) {
                    const uint4 hb = *(const uint4*)(hp + 4 * cc);
                    a0 = sd4(w8[0][4 * cc + 0], hb.x, a0);
                    a1 = sd4(w8[1][4 * cc + 0], hb.x, a1);
                    a2 = sd4(w8[2][4 * cc + 0], hb.x, a2);
                    a3 = sd4(w8[3][4 * cc + 0], hb.x, a3);
                    a0 = sd4(w8[0][4 * cc + 1], hb.y, a0);
                    a1 = sd4(w8[1][4 * cc + 1], hb.y, a1);
                    a2 = sd4(w8[2][4 * cc + 1], hb.y, a2);
                    a3 = sd4(w8[3][4 * cc + 1], hb.y, a3);
                    a0 = sd4(w8[0][4 * cc + 2], hb.z, a0);
                    a1 = sd4(w8[1][4 * cc + 2], hb.z, a1);
                    a2 = sd4(w8[2][4 * cc + 2], hb.z, a2);
                    a3 = sd4(w8[3][4 * cc + 2], hb.z, a3);
                    a0 = sd4(w8[0][4 * cc + 3], hb.w, a0);
                    a1 = sd4(w8[1][4 * cc + 3], hb.w, a1);
                    a2 = sd4(w8[2][4 * cc + 3], hb.w, a2);
                    a3 = sd4(w8[3][4 * cc + 3], hb.w, a3);
                }
                const float f0 = (float)a0 * scl[0];
                const float f1 = (float)a1 * scl[1];
                const float f2 = (float)a2 * scl[2];
                const float f3 = (float)a3 * scl[3];
                const int aa = q & 1;
                const float sendL = aa ? f0 : f1;
                const float ownL  = aa ? f1 : f0;
                const float sendH = aa ? f2 : f3;
                const float ownH  = aa ? f3 : f2;
                const float keepL = ownL + __shfl_xor(sendL, 16, 64);
                const float keepH = ownH + __shfl_xor(sendH, 16, 64);
                const int bb2 = q >> 1;
                const float send2 = bb2 ? keepL : keepH;
                const float own2  = bb2 ? keepH : keepL;
                z += own2 + __shfl_xor(send2, 32, 64);
            }
            const float h = fast_tanh(z);

            const int qv = (int)rintf(fminf(fmaxf(h * 127.f, -127.f), 127.f));
            ((char*)(hq + (t & 1) * 128))[myrow] = (char)qv;

            if (L0) {
                xrow[(size_t)t * HH] = h;              // h1 sequence in place
            } else if (t == TT - 1) {
                xrow[(size_t)t * HH] = h;              // final h2 into buf tail
            }
            xc = xn;
            xn = xn2;
            __syncthreads();
        }
        if (L0 && tid == 0) {
            __threadfence();
            __hip_atomic_store(tag_out + b * NCHUNK + c, 1u, __ATOMIC_RELEASE, AGENT);
        }
    }
}

// persistent gemm1 role: 16 tiles/WG, tile = (batch b, chunk c) = 64 rows.
// Polls h1done(b,c); stages h1 tile in LDS (full-K -> in-place safe);
// xw1 = h1 @ WT1 + bias written over the same rows; releases xw1done(b,c).
__device__ __forceinline__ void gemm_role(
    float* buf, const float* __restrict__ WT,
    const float* __restrict__ b1, const float* __restrict__ b2,
    int g, char* smem, const unsigned* tag_in, unsigned* tag_out)
{
    float* As = (float*)smem;                  // [64][512] f32 = 128 KB
    const int tid = threadIdx.x;
    const int tc = tid & 63;
    const int r0 = (tid >> 6) * 8;

    float bias[8];
    #pragma unroll
    for (int cc = 0; cc < 8; ++cc) bias[cc] = b1[tc + 64 * cc] + b2[tc + 64 * cc];

    #pragma unroll 1
    for (int it = 0; it < (NCHUNK * BB) / 128; ++it) {   // 16 tiles, chunk-major
        const int idx = g + 128 * it;
        const int c = idx >> 6, b = idx & 63;

        if (tid == 0) {
            const unsigned* tp = tag_in + b * NCHUNK + c;
            while (__hip_atomic_load(tp, __ATOMIC_ACQUIRE, AGENT) == 0u)
                __builtin_amdgcn_s_sleep(8);
        }
        __syncthreads();
        (void)__hip_atomic_load(tag_in + b * NCHUNK + c, __ATOMIC_ACQUIRE, AGENT);

        float* Ab = buf + ((size_t)b * TT + c * CHUNK) * HH;
        #pragma unroll
        for (int i = 0; i < 16; ++i) {
            const int ix = tid * 4 + i * 2048;
            *(float4*)&As[ix] = *(const float4*)&Ab[ix];
        }
        __syncthreads();

        float acc[8][8];
        #pragma unroll
        for (int cc = 0; cc < 8; ++cc)
            #pragma unroll
            for (int rr = 0; rr < 8; ++rr) acc[rr][cc] = bias[cc];

        #pragma unroll 2
        for (int k = 0; k < HH; k += 4) {
            float4 av4[8];
            #pragma unroll
            for (int rr = 0; rr < 8; ++rr)
                av4[rr] = *(const float4*)&As[(r0 + rr) * HH + k];
            #pragma unroll
            for (int kk = 0; kk < 4; ++kk) {
                float wv[8];
                #pragma unroll
                for (int cc = 0; cc < 8; ++cc)
                    wv[cc] = WT[(size_t)(k + kk) * HH + tc + 64 * cc];
                #pragma unroll
                for (int rr = 0; rr < 8; ++rr) {
                    const float a = ((const float*)&av4[rr])[kk];
                    #pragma unroll
                    for (int cc = 0; cc < 8; ++cc)
                        acc[rr][cc] = fmaf(a, wv[cc], acc[rr][cc]);
                }
            }
        }

        #pragma unroll
        for (int rr = 0; rr < 8; ++rr) {
            float* orow = Ab + (size_t)(r0 + rr) * HH;
            #pragma unroll
            for (int cc = 0; cc < 8; ++cc)
                orow[tc + 64 * cc] = acc[rr][cc];
        }
        __syncthreads();                        // all waves' stores in L2
        if (tid == 0) {
            __threadfence();
            __hip_atomic_store(tag_out + b * NCHUNK + c, 1u, __ATOMIC_RELEASE, AGENT);
        }
    }
}

__global__ __launch_bounds__(512, 1)
void pipeline_kernel(float* buf,
                     const float* __restrict__ Whh0,
                     const float* __restrict__ Whh1,
                     const float* __restrict__ WT1,
                     const float* __restrict__ bih1,
                     const float* __restrict__ bhh1,
                     unsigned* h1done, unsigned* xw1done)
{
    extern __shared__ char smem[];
    const int gid = blockIdx.x;
    if (gid < BB) {
        scan_role<true>(buf, Whh0, gid, smem, h1done, nullptr);
    } else if (gid < BB + 128) {
        gemm_role(buf, WT1, bih1, bhh1, gid - BB, smem, h1done, xw1done);
    } else {
        scan_role<false>(buf, Whh1, gid - BB - 128, smem, nullptr, xw1done);
    }
}

// -------------------- FC + softmax (h2 lives in buf0[b][T-1][:]) -------------
__global__ void fc_kernel(const float* __restrict__ buf, const float* __restrict__ w,
                          const float* __restrict__ bvec, float* __restrict__ out)
{
    const int b = threadIdx.x;   // 64 threads
    const float* h2 = buf + ((size_t)b * TT + (TT - 1)) * HH;
    float z0 = bvec[0], z1 = bvec[1];
    #pragma unroll 4
    for (int k = 0; k < HH; k += 4) {
        float4 h  = *(const float4*)&h2[k];
        float4 w0 = *(const float4*)&w[k];
        float4 w1 = *(const float4*)&w[HH + k];
        z0 += h.x * w0.x + h.y * w0.y + h.z * w0.z + h.w * w0.w;
        z1 += h.x * w1.x + h.y * w1.y + h.z * w1.z + h.w * w1.w;
    }
    const float m  = fmaxf(z0, z1);
    const float e0 = expf(z0 - m), e1 = expf(z1 - m);
    const float inv = 1.f / (e0 + e1);
    out[b * 2 + 0] = e0 * inv;
    out[b * 2 + 1] = e1 * inv;
}

extern "C" void kernel_launch(void* const* d_in, const int* in_sizes, int n_in,
                              void* d_out, int out_size, void* d_ws, size_t ws_size,
                              hipStream_t stream)
{
    (void)in_sizes; (void)n_in; (void)out_size; (void)ws_size;
    const float* x    = (const float*)d_in[0];
    const float* Wih0 = (const float*)d_in[1];
    const float* Whh0 = (const float*)d_in[2];
    const float* bih0 = (const float*)d_in[3];
    const float* bhh0 = (const float*)d_in[4];
    const float* Wih1 = (const float*)d_in[5];
    const float* Whh1 = (const float*)d_in[6];
    const float* bih1 = (const float*)d_in[7];
    const float* bhh1 = (const float*)d_in[8];
    const float* fcw  = (const float*)d_in[9];
    const float* fcb  = (const float*)d_in[10];
    float* out = (float*)d_out;

    char* ws = (char*)d_ws;
    float* buf0 = (float*)(ws + BUF0_OFF);
    float* WT   = (float*)(ws + WT_OFF);
    unsigned* tags    = (unsigned*)(ws + TAGS_OFF);
    unsigned* h1done  = tags;                 // [64][32]
    unsigned* xw1done = tags + BB * NCHUNK;   // [64][32]

    static bool attr_done = false;
    if (!attr_done) {
        (void)hipFuncSetAttribute((const void*)pipeline_kernel,
                                  hipFuncAttributeMaxDynamicSharedMemorySize, 131072);
        attr_done = true;
    }

    // tags <- 0
    zero_u32<<<dim3(16), dim3(256), 0, stream>>>(tags, 2 * BB * NCHUNK);

    // layer-0 input projection (serial, no dependency)
    transpose_w<<<dim3(IN / 32, HH / 32), dim3(256), 0, stream>>>(Wih0, WT, IN);
    gemm_xw<IN><<<dim3(MM / 32), dim3(256), 32 * IN * 4, stream>>>(x, WT, bih0, bhh0, buf0);

    // WT <- Wih1^T (after gemm0: stream-ordered, no race)
    transpose_w<<<dim3(HH / 32, HH / 32), dim3(256), 0, stream>>>(Wih1, WT, HH);

    // fused pipeline: scan0 (64) || gemm1 (128) || scan1 (64)
    pipeline_kernel<<<dim3(256), dim3(512), 131072, stream>>>(
        buf0, Whh0, Whh1, WT, bih1, bhh1, h1done, xw1done);

    // FC + softmax
    fc_kernel<<<dim3(1), dim3(64), 0, stream>>>(buf0, fcw, fcb, out);
}